// Round 7
// baseline (717.299 us; speedup 1.0000x reference)
//
#include <hip/hip_runtime.h>
#include <cstdint>

#define SEQ 2048
#define ED  2048
#define NHEADS 32
#define NKV 8
#define HD 64
#define KVD 512   // NKV*HD

typedef __attribute__((ext_vector_type(8))) short short8;
typedef __attribute__((ext_vector_type(8))) unsigned short ushort8;
typedef __attribute__((ext_vector_type(4))) float f32x4;

#define QSCALE (0.125f*1.44269504088896f)

__device__ __forceinline__ float bf2f(unsigned short u){ return __uint_as_float(((unsigned)u)<<16); }
__device__ __forceinline__ unsigned short f2bf(float f){
  unsigned x = __float_as_uint(f);
  return (unsigned short)((x + 0x7fffu + ((x>>16)&1u)) >> 16);
}
__device__ __forceinline__ float fexp2(float x){ float r; asm("v_exp_f32 %0, %1":"=v"(r):"v"(x)); return r; }

__device__ __forceinline__ void gld_lds16(const void* g, void* l){
  __builtin_amdgcn_global_load_lds((const __attribute__((address_space(1))) unsigned*)g,
                                   (__attribute__((address_space(3))) unsigned*)l, 16, 0, 0);
}

// ---------------- fp32 -> bf16 converts ----------------
__global__ __launch_bounds__(256) void cvt_main(const float* __restrict__ Xq, const float* __restrict__ Xkv,
                                                const float* __restrict__ wq, const float* __restrict__ wk,
                                                const float* __restrict__ wv,
                                                unsigned short* __restrict__ Xb, unsigned short* __restrict__ KVb,
                                                unsigned short* __restrict__ Wqb, unsigned short* __restrict__ WKVb){
  int b = blockIdx.x;
  const float* src; unsigned short* dst;
  if (b < 2048)      { src = Xq;  dst = Xb; }
  else if (b < 4096) { src = Xkv; dst = KVb;  b -= 2048; }
  else if (b < 6144) { src = wq;  dst = Wqb;  b -= 4096; }
  else if (b < 6656) { src = wk;  dst = WKVb; b -= 6144; }
  else               { src = wv;  dst = WKVb + (size_t)512*ED; b -= 6656; }
  size_t t = (size_t)b*256 + threadIdx.x;
  const f32x4* p = (const f32x4*)src + t*2;
  f32x4 a = p[0], c = p[1];
  ushort8 o;
  o[0]=f2bf(a[0]); o[1]=f2bf(a[1]); o[2]=f2bf(a[2]); o[3]=f2bf(a[3]);
  o[4]=f2bf(c[0]); o[5]=f2bf(c[1]); o[6]=f2bf(c[2]); o[7]=f2bf(c[3]);
  *(ushort8*)(dst + t*8) = o;
}

__global__ __launch_bounds__(256) void cvt_wo(const float* __restrict__ wo, unsigned short* __restrict__ Wob){
  size_t t = (size_t)blockIdx.x*256 + threadIdx.x;
  const f32x4* p = (const f32x4*)wo + t*2;
  f32x4 a = p[0], c = p[1];
  ushort8 o;
  o[0]=f2bf(a[0]); o[1]=f2bf(a[1]); o[2]=f2bf(a[2]); o[3]=f2bf(a[3]);
  o[4]=f2bf(c[0]); o[5]=f2bf(c[1]); o[6]=f2bf(c[2]); o[7]=f2bf(c[3]);
  *(ushort8*)(Wob + t*8) = o;
}

// ---------------- split-K GEMM (3-stage ring, counted vmcnt), flag-combine epilogue ----------------
// EPI 0: Q-proj  -> combine + RoPE + QSCALE -> Qb bf16 [2048][2048]
// EPI 1: KV-proj -> n0<512: combine + RoPE -> Kb bf16 [2048][512];
//                   n0>=512: combine + key-interleave -> Vtb bf16 [512][2048]
// EPI 2: O-proj  -> fp32 partials, combine -> out fp32 [2048][2048]
template<int EPI>
__device__ __forceinline__ void gemm_split(const unsigned short* __restrict__ A,
                                           const unsigned short* __restrict__ B,
                                           int bx, int by, int ks, int* __restrict__ flag,
                                           unsigned short* __restrict__ Pb0, unsigned short* __restrict__ Pb1,
                                           float* __restrict__ Pf,
                                           unsigned short* __restrict__ F0, unsigned short* __restrict__ F1,
                                           float* __restrict__ Fout,
                                           const float* __restrict__ cosT, const float* __restrict__ sinT,
                                           unsigned short* As, unsigned short* Bs, int* who_s){
  const int tid = threadIdx.x;
  const int lane = tid & 63;
  const int wave = tid >> 6;
  const int wr = wave >> 1, wc = wave & 1;
  const int m0 = by * 128, n0 = bx * 128;
  const int l15 = lane & 15, l4 = lane >> 4;
  const int kbase = ks * (ED/2);

  f32x4 acc[4][4] = {};

  const int arow0 = tid>>2,        sc0 = tid&3, oc0 = sc0 ^ ((arow0>>1) & 3);
  const int arow1 = (tid+256)>>2,  oc1 = sc0 ^ ((arow1>>1) & 3);
  const unsigned short* Ag0 = A + (size_t)(m0+arow0)*ED + kbase + oc0*8;
  const unsigned short* Ag1 = A + (size_t)(m0+arow1)*ED + kbase + oc1*8;
  const unsigned short* Bg0 = B + (size_t)(n0+arow0)*ED + kbase + oc0*8;
  const unsigned short* Bg1 = B + (size_t)(n0+arow1)*ED + kbase + oc1*8;

  const int nk = (ED/2) >> 5;   // 32

#define GSTAGE(buf_, kt_) { \
    const int ko_ = (kt_)*32; const int bo_ = (buf_)*4096; \
    gld_lds16(Ag0 + ko_, As + bo_ + tid*8); \
    gld_lds16(Ag1 + ko_, As + bo_ + (tid+256)*8); \
    gld_lds16(Bg0 + ko_, Bs + bo_ + tid*8); \
    gld_lds16(Bg1 + ko_, Bs + bo_ + (tid+256)*8); }

  GSTAGE(0, 0);
  GSTAGE(1, 1);

  for(int kt=0; kt<nk; kt++){
    if (kt+1 == nk) { asm volatile("s_waitcnt vmcnt(0)" ::: "memory"); }
    else            { asm volatile("s_waitcnt vmcnt(4)" ::: "memory"); }
    __builtin_amdgcn_s_barrier();
    __builtin_amdgcn_sched_barrier(0);

    if (kt+2 < nk) GSTAGE((kt+2)%3, kt+2);

    const int cur = (kt%3)*4096;
    short8 af[4], bfr[4];
#pragma unroll
    for(int m=0;m<4;m++){
      int row = wr*64 + m*16 + l15;
      af[m] = *(const short8*)&As[cur + row*32 + ((l4 ^ ((row>>1)&3))*8)];
    }
#pragma unroll
    for(int n=0;n<4;n++){
      int row = wc*64 + n*16 + l15;
      bfr[n] = *(const short8*)&Bs[cur + row*32 + ((l4 ^ ((row>>1)&3))*8)];
    }
    __builtin_amdgcn_s_setprio(1);
#pragma unroll
    for(int m=0;m<4;m++)
#pragma unroll
      for(int n=0;n<4;n++)
        acc[m][n] = __builtin_amdgcn_mfma_f32_16x16x32_bf16(af[m], bfr[n], acc[m][n], 0,0,0);
    __builtin_amdgcn_s_setprio(0);
  }
#undef GSTAGE

  // ---- write own partial ----
#pragma unroll
  for(int m=0;m<4;m++){
    const int row0 = m0 + wr*64 + m*16 + l4*4;
#pragma unroll
    for(int n=0;n<4;n++){
      const int col = n0 + wc*64 + n*16 + l15;
      if constexpr (EPI == 2){
        float* P = Pf + (size_t)ks*SEQ*ED;
#pragma unroll
        for(int r=0;r<4;r++) P[(size_t)(row0+r)*ED + col] = acc[m][n][r];
      } else if constexpr (EPI == 0){
        unsigned short* P = Pb0 + (size_t)ks*SEQ*ED;
#pragma unroll
        for(int r=0;r<4;r++) P[(size_t)(row0+r)*ED + col] = f2bf(acc[m][n][r]);
      } else {
        const bool isK = (n0 < 512);
        unsigned short* P = (isK ? Pb0 : Pb1) + (size_t)ks*SEQ*KVD;
        const int cp = col - (isK ? 0 : 512);
#pragma unroll
        for(int r=0;r<4;r++) P[(size_t)(row0+r)*KVD + cp] = f2bf(acc[m][n][r]);
      }
    }
  }

  // ---- release/acquire flag ----
  __threadfence();
  __syncthreads();
  if (tid == 0) *who_s = atomicAdd(flag, 1);
  __syncthreads();
  if (!*who_s) return;
  __threadfence();

  // ---- combine + transform + final write ----
#pragma unroll
  for(int m=0;m<4;m++){
    const int row0 = m0 + wr*64 + m*16 + l4*4;
#pragma unroll
    for(int n=0;n<4;n++){
      const int col = n0 + wc*64 + n*16 + l15;
      if constexpr (EPI == 0){
        const unsigned short* Po = Pb0 + (size_t)(ks^1)*SEQ*ED;
#pragma unroll
        for(int r=0;r<4;r++){
          const int row = row0 + r;
          float x = bf2f(f2bf(acc[m][n][r])) + bf2f(Po[(size_t)row*ED + col]);
          float xo = __shfl_xor(x, 1);
          const int jh = (col & 63) >> 1;
          float cc = cosT[row*32 + jh], ss = sinT[row*32 + jh];
          float res = (l15 & 1) ? fmaf(xo, ss, x*cc) : (x*cc - xo*ss);
          F0[(size_t)row*ED + col] = f2bf(res * QSCALE);
        }
      } else if constexpr (EPI == 1){
        const bool isK = (n0 < 512);
        const unsigned short* Po = (isK ? Pb0 : Pb1) + (size_t)(ks^1)*SEQ*KVD;
        const int cp = col - (isK ? 0 : 512);
#pragma unroll
        for(int r=0;r<4;r++){
          const int row = row0 + r;
          float x = bf2f(f2bf(acc[m][n][r])) + bf2f(Po[(size_t)row*KVD + cp]);
          if (isK){
            float xo = __shfl_xor(x, 1);
            const int jh = (col & 63) >> 1;
            float cc = cosT[row*32 + jh], ss = sinT[row*32 + jh];
            float res = (l15 & 1) ? fmaf(xo, ss, x*cc) : (x*cc - xo*ss);
            F0[(size_t)row*KVD + col] = f2bf(res);
          } else {
            const int seq = row;
            const int pos = ((seq>>5)&1)*32 + (seq&15)*2 + ((seq>>4)&1);
            F1[(size_t)cp*SEQ + (seq & ~63) + pos] = f2bf(x);
          }
        }
      } else {
        const float* Po = Pf + (size_t)(ks^1)*SEQ*ED;
#pragma unroll
        for(int r=0;r<4;r++){
          const int row = row0 + r;
          Fout[(size_t)row*ED + col] = acc[m][n][r] + Po[(size_t)row*ED + col];
        }
      }
    }
  }
}

// Q-proj (blocks 0..511: 256 tiles x 2 ksplit) + KV-proj (512..767: 128 tiles x 2)
__global__ __launch_bounds__(256) void gemm_proj(const unsigned short* __restrict__ Xb,
                                                 const unsigned short* __restrict__ Wqb,
                                                 const unsigned short* __restrict__ KVb,
                                                 const unsigned short* __restrict__ WKVb,
                                                 unsigned short* __restrict__ Qp,
                                                 unsigned short* __restrict__ Kp,
                                                 unsigned short* __restrict__ Vp,
                                                 unsigned short* __restrict__ Qb,
                                                 unsigned short* __restrict__ Kb,
                                                 unsigned short* __restrict__ Vtb,
                                                 int* __restrict__ flags,
                                                 const float* __restrict__ cq, const float* __restrict__ sq,
                                                 const float* __restrict__ ck, const float* __restrict__ sk){
  __shared__ unsigned short As[3*4096];
  __shared__ unsigned short Bs[3*4096];
  __shared__ int who_s;
  int b = blockIdx.x;
  if (b < 512){
    int ks = b >> 8, t = b & 255;
    gemm_split<0>(Xb, Wqb, t&15, t>>4, ks, flags + t,
                  Qp, nullptr, nullptr, Qb, nullptr, nullptr, cq, sq, As, Bs, &who_s);
  } else {
    int bb = b - 512;
    int ks = bb >> 7, t = bb & 127;
    gemm_split<1>(KVb, WKVb, t&7, t>>3, ks, flags + 256 + t,
                  Kp, Vp, nullptr, Kb, Vtb, nullptr, ck, sk, As, Bs, &who_s);
  }
}

__global__ __launch_bounds__(256) void gemm_out_k(const unsigned short* __restrict__ Obf,
                                                  const unsigned short* __restrict__ Wob,
                                                  float* __restrict__ Op,
                                                  float* __restrict__ out,
                                                  int* __restrict__ flags){
  __shared__ unsigned short As[3*4096];
  __shared__ unsigned short Bs[3*4096];
  __shared__ int who_s;
  int b = blockIdx.x;
  int ks = b >> 8, t = b & 255;
  gemm_split<2>(Obf, Wob, t&15, t>>4, ks, flags + 1024 + t,
                nullptr, nullptr, Op, nullptr, nullptr, out, nullptr, nullptr, As, Bs, &who_s);
}

// ---------------- flash attention: split-KV=2, 128 q-rows/block, flag-combine ----------------
__global__ __launch_bounds__(256) void attn_k(const unsigned short* __restrict__ Qb,
                                              const unsigned short* __restrict__ Kb,
                                              const unsigned short* __restrict__ Vt,
                                              float* __restrict__ Oa,
                                              float* __restrict__ La,
                                              unsigned short* __restrict__ Ob,
                                              int* __restrict__ flags){
  __shared__ unsigned short Ks[2][4096];
  __shared__ unsigned short Vs[2][4096];
  __shared__ unsigned Psu[4][1024];
  __shared__ int who_s;
  const int tid = threadIdx.x, lane = tid & 63, w = tid >> 6;
  const int l15 = lane & 15, l4 = lane >> 4;
  const int qb = blockIdx.x, h = blockIdx.y, z = blockIdx.z, kvh = h & 7;

  const int row = tid>>3, sc = tid&7, oc = sc ^ (row&7);
  const int row2 = row + 32, oc2 = sc ^ (row2&7);
  const unsigned short* Kg0 = Kb + (size_t)row*KVD  + kvh*HD + oc*8;
  const unsigned short* Kg1 = Kb + (size_t)row2*KVD + kvh*HD + oc2*8;
  const unsigned short* Vg0 = Vt + (size_t)(kvh*HD+row)*SEQ  + oc*8;
  const unsigned short* Vg1 = Vt + (size_t)(kvh*HD+row2)*SEQ + oc2*8;

#define ATTN_STAGE(buf, kb_) { \
    const size_t koff = (size_t)(kb_)*64*KVD; const int voff = (kb_)*64; \
    gld_lds16(Kg0 + koff, &Ks[buf][tid*8]); \
    gld_lds16(Kg1 + koff, &Ks[buf][(tid+256)*8]); \
    gld_lds16(Vg0 + voff, &Vs[buf][tid*8]); \
    gld_lds16(Vg1 + voff, &Vs[buf][(tid+256)*8]); }

  const int kb0 = z*16;
  ATTN_STAGE(0, kb0);

  short8 qa[2][2];
  {
    const unsigned short* qp0 = Qb + (size_t)(qb*128 + w*32 + l15)*ED + h*HD + l4*8;
    qa[0][0] = *(const short8*)qp0;
    qa[0][1] = *(const short8*)(qp0 + 32);
    const unsigned short* qp1 = qp0 + (size_t)16*ED;
    qa[1][0] = *(const short8*)qp1;
    qa[1][1] = *(const short8*)(qp1 + 32);
  }

  unsigned* Pw = &Psu[w][0];
  f32x4 o_acc[2][4] = {};
  float l_acc[2][4] = {{0.f,0.f,0.f,0.f},{0.f,0.f,0.f,0.f}};
  __syncthreads();

  for(int i=0; i<16; i++){
    const int cur = i & 1;
    if (i+1 < 16) ATTN_STAGE(cur^1, kb0+i+1);

    __builtin_amdgcn_s_setprio(1);
    f32x4 s_acc[2][4] = {};
#pragma unroll
    for(int n=0;n<4;n++){
      int key = n*16 + l15;
#pragma unroll
      for(int ks=0;ks<2;ks++){
        short8 kf = *(const short8*)&Ks[cur][key*64 + (((ks*4+l4) ^ (key&7))*8)];
        s_acc[0][n] = __builtin_amdgcn_mfma_f32_16x16x32_bf16(qa[0][ks], kf, s_acc[0][n], 0,0,0);
        s_acc[1][n] = __builtin_amdgcn_mfma_f32_16x16x32_bf16(qa[1][ks], kf, s_acc[1][n], 0,0,0);
      }
    }
    __builtin_amdgcn_s_setprio(0);

#pragma unroll
    for(int mt=0;mt<2;mt++){
#pragma unroll
      for(int r=0;r<4;r++){
        float p0 = fexp2(s_acc[mt][0][r]), p1 = fexp2(s_acc[mt][1][r]);
        float p2 = fexp2(s_acc[mt][2][r]), p3 = fexp2(s_acc[mt][3][r]);
        l_acc[mt][r] += (p0+p1)+(p2+p3);
        unsigned u01, u23;
        asm("v_cvt_pk_bf16_f32 %0, %1, %2" : "=v"(u01) : "v"(p0), "v"(p1));
        asm("v_cvt_pk_bf16_f32 %0, %1, %2" : "=v"(u23) : "v"(p2), "v"(p3));
        const int q32 = mt*16 + l4*4 + r;
        Pw[q32*32 + (((l15>>2)     ^ (q32&7))<<2) + (l15&3)] = u01;
        Pw[q32*32 + (((4+(l15>>2)) ^ (q32&7))<<2) + (l15&3)] = u23;
      }
    }
    asm volatile("s_waitcnt lgkmcnt(0)" ::: "memory");

    __builtin_amdgcn_s_setprio(1);
#pragma unroll
    for(int ks=0;ks<2;ks++){
      short8 pa0 = *(const short8*)&Pw[(l15   )*32 + (((ks*4+l4) ^ (l15&7))<<2)];
      short8 pa1 = *(const short8*)&Pw[(16+l15)*32 + (((ks*4+l4) ^ (l15&7))<<2)];
#pragma unroll
      for(int n=0;n<4;n++){
        int d = n*16 + l15;
        short8 vf = *(const short8*)&Vs[cur][d*64 + (((ks*4+l4) ^ (d&7))*8)];
        o_acc[0][n] = __builtin_amdgcn_mfma_f32_16x16x32_bf16(pa0, vf, o_acc[0][n], 0,0,0);
        o_acc[1][n] = __builtin_amdgcn_mfma_f32_16x16x32_bf16(pa1, vf, o_acc[1][n], 0,0,0);
      }
    }
    __builtin_amdgcn_s_setprio(0);
    __syncthreads();
  }
#undef ATTN_STAGE

  // reduce denominators across 16-lane key groups (row totals, unnormalized)
#pragma unroll
  for(int mt=0;mt<2;mt++)
#pragma unroll
    for(int r=0;r<4;r++){
      float t = l_acc[mt][r];
      t += __shfl_xor(t,1); t += __shfl_xor(t,2); t += __shfl_xor(t,4); t += __shfl_xor(t,8);
      l_acc[mt][r] = t;
    }

  // ---- write own partial (unnormalized O fp32, row-sum l) ----
  float* OaZ = Oa + (size_t)z*SEQ*ED;
  float* LaZ = La + (size_t)z*NHEADS*SEQ + (size_t)h*SEQ;
#pragma unroll
  for(int mt=0;mt<2;mt++)
#pragma unroll
    for(int n=0;n<4;n++){
      const int col = h*HD + n*16 + l15;
#pragma unroll
      for(int r=0;r<4;r++){
        const int srow = qb*128 + w*32 + mt*16 + l4*4 + r;
        OaZ[(size_t)srow*ED + col] = o_acc[mt][n][r];
      }
    }
  if (l15 == 0){
#pragma unroll
    for(int mt=0;mt<2;mt++)
#pragma unroll
      for(int r=0;r<4;r++)
        LaZ[qb*128 + w*32 + mt*16 + l4*4 + r] = l_acc[mt][r];
  }

  __threadfence();
  __syncthreads();
  if (tid == 0) who_s = atomicAdd(&flags[h*16 + qb], 1);
  __syncthreads();
  if (!who_s) return;
  __threadfence();

  // ---- combine: O = (o_own + o_other) / (l_own + l_other), write bf16 ----
  const float* OaO = Oa + (size_t)(z^1)*SEQ*ED;
  const float* LaO = La + (size_t)(z^1)*NHEADS*SEQ + (size_t)h*SEQ;
  float inv[2][4];
#pragma unroll
  for(int mt=0;mt<2;mt++)
#pragma unroll
    for(int r=0;r<4;r++){
      const int srow = qb*128 + w*32 + mt*16 + l4*4 + r;
      inv[mt][r] = 1.0f / (l_acc[mt][r] + LaO[srow]);
    }
#pragma unroll
  for(int mt=0;mt<2;mt++)
#pragma unroll
    for(int n=0;n<4;n++){
      const int col = h*HD + n*16 + l15;
#pragma unroll
      for(int r=0;r<4;r++){
        const int srow = qb*128 + w*32 + mt*16 + l4*4 + r;
        float tot = o_acc[mt][n][r] + OaO[(size_t)srow*ED + col];
        Ob[(size_t)srow*ED + col] = f2bf(tot * inv[mt][r]);
      }
    }
}

extern "C" void kernel_launch(void* const* d_in, const int* in_sizes, int n_in,
                              void* d_out, int out_size, void* d_ws, size_t ws_size,
                              hipStream_t stream) {
  const float* Xq    = (const float*)d_in[0];
  const float* Xkv   = (const float*)d_in[1];
  const float* cos_q = (const float*)d_in[2];
  const float* sin_q = (const float*)d_in[3];
  const float* cos_k = (const float*)d_in[4];
  const float* sin_k = (const float*)d_in[5];
  const float* wq = (const float*)d_in[7];
  const float* wk = (const float*)d_in[8];
  const float* wv = (const float*)d_in[9];
  const float* wo = (const float*)d_in[10];
  float* out = (float*)d_out;

  char* ws = (char*)d_ws;
  const size_t MB = 1u<<20;
  // flags: [0..256) Q tiles, [256..384) KV tiles, [512..1024) attn tiles, [1024..1280) out tiles
  int* flags = (int*)ws;
  unsigned short* Xb   = (unsigned short*)(ws + 1*MB);   // bf16 [2048][2048]
  unsigned short* KVb  = (unsigned short*)(ws + 9*MB);   // bf16 [2048][2048]
  unsigned short* Wqb  = (unsigned short*)(ws + 17*MB);  // bf16 [2048][2048]
  unsigned short* WKVb = (unsigned short*)(ws + 25*MB);  // bf16 [1024][2048]
  unsigned short* Qp   = (unsigned short*)(ws + 29*MB);  // bf16 [2][2048][2048] partials
  unsigned short* Kp   = (unsigned short*)(ws + 45*MB);  // bf16 [2][2048][512]
  unsigned short* Vp   = (unsigned short*)(ws + 49*MB);  // bf16 [2][2048][512]
  unsigned short* Qb   = (unsigned short*)(ws + 53*MB);  // bf16 [2048][2048]
  unsigned short* Kb   = (unsigned short*)(ws + 61*MB);  // bf16 [2048][512]
  unsigned short* Vtb  = (unsigned short*)(ws + 63*MB);  // bf16 [512][2048]  (peak 65MB)
  float*          Oa   = (float*)(ws + 1*MB);            // f32 [2][2048][2048] (aliases dead inputs)
  float*          La   = (float*)(ws + 33*MB);           // f32 [2][32][2048]
  unsigned short* Obf  = (unsigned short*)(ws + 34*MB);  // bf16 [2048][2048] (aliases dead Qp)
  unsigned short* Wob  = (unsigned short*)(ws + 42*MB);  // bf16 [2048][2048] (aliases dead Qp/Kp/Vp)
  float*          Op   = (float*)(ws + 1*MB);            // f32 [2][2048][2048] (aliases dead Oa)

  hipMemsetAsync(ws, 0, 8192, stream);

  cvt_main<<<7168,256,0,stream>>>(Xq, Xkv, wq, wk, wv, Xb, KVb, Wqb, WKVb);

  gemm_proj<<<768,256,0,stream>>>(Xb, Wqb, KVb, WKVb, Qp, Kp, Vp, Qb, Kb, Vtb,
                                  flags, cos_q, sin_q, cos_k, sin_k);

  cvt_wo<<<2048,256,0,stream>>>(wo, Wob);

  attn_k<<<dim3(SEQ/128, NHEADS, 2),256,0,stream>>>(Qb, Kb, Vtb, Oa, La, Obf, flags + 512);

  gemm_out_k<<<512,256,0,stream>>>(Obf, Wob, Op, out, flags);
}

// Round 9
// 259.266 us; speedup vs baseline: 2.7667x; 2.7667x over previous
//
#include <hip/hip_runtime.h>
#include <cstdint>

#define SEQ 2048
#define ED  2048
#define NHEADS 32
#define NKV 8
#define HD 64
#define KVD 512   // NKV*HD

typedef __attribute__((ext_vector_type(8))) short short8;
typedef __attribute__((ext_vector_type(8))) unsigned short ushort8;
typedef __attribute__((ext_vector_type(4))) float f32x4;

__device__ __forceinline__ float bf2f(unsigned short u){ return __uint_as_float(((unsigned)u)<<16); }
__device__ __forceinline__ unsigned short f2bf(float f){
  unsigned x = __float_as_uint(f);
  return (unsigned short)((x + 0x7fffu + ((x>>16)&1u)) >> 16);
}
__device__ __forceinline__ float fexp2(float x){ float r; asm("v_exp_f32 %0, %1":"=v"(r):"v"(x)); return r; }

__device__ __forceinline__ void gld_lds16(const void* g, void* l){
  __builtin_amdgcn_global_load_lds((const __attribute__((address_space(1))) unsigned*)g,
                                   (__attribute__((address_space(3))) unsigned*)l, 16, 0, 0);
}

// ---------------- fused fp32 -> bf16 convert ----------------
__global__ __launch_bounds__(256) void cvt_all(const float* __restrict__ Xq, const float* __restrict__ Xkv,
                                               const float* __restrict__ wq, const float* __restrict__ wk,
                                               const float* __restrict__ wv, const float* __restrict__ wo,
                                               unsigned short* __restrict__ Xb, unsigned short* __restrict__ KVb,
                                               unsigned short* __restrict__ Wqb, unsigned short* __restrict__ WKVb,
                                               unsigned short* __restrict__ Wob){
  int b = blockIdx.x;
  const float* src; unsigned short* dst;
  if (b < 2048)      { src = Xq;  dst = Xb; }
  else if (b < 4096) { src = Xkv; dst = KVb;  b -= 2048; }
  else if (b < 6144) { src = wq;  dst = Wqb;  b -= 4096; }
  else if (b < 6656) { src = wk;  dst = WKVb; b -= 6144; }
  else if (b < 7168) { src = wv;  dst = WKVb + (size_t)512*ED; b -= 6656; }
  else               { src = wo;  dst = Wob;  b -= 7168; }
  size_t t = (size_t)b*256 + threadIdx.x;
  const f32x4* p = (const f32x4*)src + t*2;
  f32x4 a = p[0], c = p[1];
  ushort8 o;
  o[0]=f2bf(a[0]); o[1]=f2bf(a[1]); o[2]=f2bf(a[2]); o[3]=f2bf(a[3]);
  o[4]=f2bf(c[0]); o[5]=f2bf(c[1]); o[6]=f2bf(c[2]); o[7]=f2bf(c[3]);
  *(ushort8*)(dst + t*8) = o;
}

// ---------------- merged RoPE for Q and K (in-place on bf16) ----------------
__global__ __launch_bounds__(256) void rope_all(unsigned short* __restrict__ Qb, unsigned short* __restrict__ Kbuf,
                                                const float* __restrict__ cq, const float* __restrict__ sq,
                                                const float* __restrict__ ck, const float* __restrict__ sk){
  int b = blockIdx.x;
  unsigned short* buf; const float* cosT; const float* sinT; int lw; float scale;
  if (b < 2048){ buf=Qb; cosT=cq; sinT=sq; lw=11; scale=0.125f*1.44269504088896f; }
  else { b -= 2048; buf=Kbuf; cosT=ck; sinT=sk; lw=9; scale=1.0f; }
  int t = b*256 + threadIdx.x;
  int e = t*8;
  int s = e >> lw;
  int col = e & ((1<<lw)-1);
  int i0 = (col & 63) >> 1;
  ushort8 v = *(ushort8*)(buf + e);
  f32x4 c  = *(const f32x4*)(cosT + s*32 + i0);
  f32x4 sn = *(const f32x4*)(sinT + s*32 + i0);
  ushort8 o;
#pragma unroll
  for(int p=0;p<4;p++){
    float x1 = bf2f(v[2*p]), x2 = bf2f(v[2*p+1]);
    o[2*p]   = f2bf((x1*c[p] - x2*sn[p])*scale);
    o[2*p+1] = f2bf((x1*sn[p] + x2*c[p])*scale);
  }
  *(ushort8*)(buf + e) = o;
}

// ---------------- 64x128-tile GEMM, ring-4 LDS, 3-ahead prefetch, counted vmcnt ----------------
// C[m][n] = sum_k A[m*K+k]*B[n*K+k]
// EPI 0: bf16 [M][N]; EPI 2: fp32 [M][N];
// EPI 3: n<512 -> K bf16 [M][512]; n>=512 -> V^T key-interleaved bf16 [512][SEQ] into Cout2
template<int EPI>
__device__ __forceinline__ void gemm_body(const unsigned short* __restrict__ A,
                                          const unsigned short* __restrict__ B,
                                          void* __restrict__ Cout, void* __restrict__ Cout2,
                                          int M, int N, int K, int bx, int by,
                                          unsigned short* As, unsigned short* Bs){
  const int tid = threadIdx.x;
  const int lane = tid & 63;
  const int wave = tid >> 6;
  const int wr = wave >> 1, wc = wave & 1;
  const int m0 = by * 64, n0 = bx * 128;
  const int l15 = lane & 15, l4 = lane >> 4;

  f32x4 acc[2][4] = {};

  // A: 64 rows x 4 chunks, 1 load/thread. B: 128 rows, 2 loads/thread.
  const int arow = tid>>2, sc0 = tid&3;
  const int aoc  = sc0 ^ ((arow>>1)&3);
  const int brow1 = (tid+256)>>2;
  const int boc1  = sc0 ^ ((brow1>>1)&3);
  const unsigned short* Ag  = A + (size_t)(m0+arow)*K  + aoc*8;
  const unsigned short* Bg0 = B + (size_t)(n0+arow)*K  + aoc*8;
  const unsigned short* Bg1 = B + (size_t)(n0+brow1)*K + boc1*8;

  const int nk = K >> 5;   // 64

#define GSTAGE(buf_, kt_) { \
    const int ko_ = (kt_)*32; \
    gld_lds16(Ag  + ko_, As + (buf_)*2048 + tid*8); \
    gld_lds16(Bg0 + ko_, Bs + (buf_)*4096 + tid*8); \
    gld_lds16(Bg1 + ko_, Bs + (buf_)*4096 + (tid+256)*8); }

  GSTAGE(0, 0);
  GSTAGE(1, 1);
  GSTAGE(2, 2);

  for(int kt=0; kt<nk; kt++){
    if (kt+1 == nk)      { asm volatile("s_waitcnt vmcnt(0)" ::: "memory"); }
    else if (kt+2 == nk) { asm volatile("s_waitcnt vmcnt(3)" ::: "memory"); }
    else                 { asm volatile("s_waitcnt vmcnt(6)" ::: "memory"); }
    __builtin_amdgcn_s_barrier();
    __builtin_amdgcn_sched_barrier(0);

    if (kt+3 < nk) GSTAGE((kt+3)&3, kt+3);

    const int curA = (kt&3)*2048, curB = (kt&3)*4096;
    short8 af[2], bfr[4];
#pragma unroll
    for(int m=0;m<2;m++){
      int row = wr*32 + m*16 + l15;
      af[m] = *(const short8*)&As[curA + row*32 + ((l4 ^ ((row>>1)&3))*8)];
    }
#pragma unroll
    for(int n=0;n<4;n++){
      int row = wc*64 + n*16 + l15;
      bfr[n] = *(const short8*)&Bs[curB + row*32 + ((l4 ^ ((row>>1)&3))*8)];
    }
    __builtin_amdgcn_s_setprio(1);
#pragma unroll
    for(int m=0;m<2;m++)
#pragma unroll
      for(int n=0;n<4;n++)
        acc[m][n] = __builtin_amdgcn_mfma_f32_16x16x32_bf16(af[m], bfr[n], acc[m][n], 0,0,0);
    __builtin_amdgcn_s_setprio(0);
  }
#undef GSTAGE

#pragma unroll
  for(int m=0;m<2;m++){
    const int row0 = m0 + wr*32 + m*16 + l4*4;
#pragma unroll
    for(int n=0;n<4;n++){
      const int col = n0 + wc*64 + n*16 + l15;
      if constexpr (EPI == 0){
        unsigned short* C = (unsigned short*)Cout;
#pragma unroll
        for(int r=0;r<4;r++) C[(size_t)(row0+r)*N + col] = f2bf(acc[m][n][r]);
      } else if constexpr (EPI == 2){
        float* C = (float*)Cout;
#pragma unroll
        for(int r=0;r<4;r++) C[(size_t)(row0+r)*N + col] = acc[m][n][r];
      } else { // EPI == 3
        if (n0 < 512){
          unsigned short* C = (unsigned short*)Cout;
#pragma unroll
          for(int r=0;r<4;r++) C[(size_t)(row0+r)*512 + col] = f2bf(acc[m][n][r]);
        } else {
          unsigned short* C = (unsigned short*)Cout2;
          const int d = col - 512;
#pragma unroll
          for(int r=0;r<4;r++){
            int seq = row0 + r;
            // key-interleave within each 64-block: key=32ks+p+16s -> pos=32ks+2p+s
            int pos = ((seq>>5)&1)*32 + (seq&15)*2 + ((seq>>4)&1);
            C[(size_t)d*SEQ + (seq & ~63) + pos] = f2bf(acc[m][n][r]);
          }
        }
      }
    }
  }
}

// Q-proj (blocks 0..511: 32 my x 16 nx) + KV-proj (512..767: 32 my x 8 nx)
__global__ __launch_bounds__(256) void gemm_proj(const unsigned short* __restrict__ Xb,
                                                 const unsigned short* __restrict__ Wqb,
                                                 const unsigned short* __restrict__ KVb,
                                                 const unsigned short* __restrict__ WKVb,
                                                 unsigned short* __restrict__ Qb,
                                                 unsigned short* __restrict__ Kb,
                                                 unsigned short* __restrict__ Vtb){
  __shared__ unsigned short As[4*2048];
  __shared__ unsigned short Bs[4*4096];
  int b = blockIdx.x;
  if (b < 512){
    gemm_body<0>(Xb, Wqb, Qb, nullptr, SEQ, ED, ED, b&15, b>>4, As, Bs);
  } else {
    int bb = b - 512;
    gemm_body<3>(KVb, WKVb, Kb, Vtb, SEQ, 1024, ED, bb&7, bb>>3, As, Bs);
  }
}

__global__ __launch_bounds__(256) void gemm_out_k(const unsigned short* __restrict__ Obf,
                                                  const unsigned short* __restrict__ Wob,
                                                  float* __restrict__ out){
  __shared__ unsigned short As[4*2048];
  __shared__ unsigned short Bs[4*4096];
  int b = blockIdx.x;
  gemm_body<2>(Obf, Wob, out, nullptr, SEQ, ED, ED, b&15, b>>4, As, Bs);
}

// ---------------- flash attention: 128 q-rows/block (32/wave), 2-phase K/V, packed P ----------------
__global__ __launch_bounds__(256) void attn_k(const unsigned short* __restrict__ Qb,
                                              const unsigned short* __restrict__ Kb,
                                              const unsigned short* __restrict__ Vt,
                                              unsigned short* __restrict__ Ob){
  __shared__ unsigned short Ks[2][4096];
  __shared__ unsigned short Vs[2][4096];
  __shared__ unsigned Psu[4][1024];          // per-wave: 32 rows x 32 u32 words
  const int tid = threadIdx.x, lane = tid & 63, w = tid >> 6;
  const int l15 = lane & 15, l4 = lane >> 4;
  const int qb = blockIdx.x, h = blockIdx.y, kvh = h & 7;

  const int row = tid>>3, sc = tid&7, oc = sc ^ (row&7);
  const int row2 = row + 32, oc2 = sc ^ (row2&7);
  const unsigned short* Kg0 = Kb + (size_t)row*KVD  + kvh*HD + oc*8;
  const unsigned short* Kg1 = Kb + (size_t)row2*KVD + kvh*HD + oc2*8;
  const unsigned short* Vg0 = Vt + (size_t)(kvh*HD+row)*SEQ  + oc*8;
  const unsigned short* Vg1 = Vt + (size_t)(kvh*HD+row2)*SEQ + oc2*8;

#define ATTN_STAGE(buf, kb_) { \
    const size_t koff = (size_t)(kb_)*64*KVD; const int voff = (kb_)*64; \
    gld_lds16(Kg0 + koff, &Ks[buf][tid*8]); \
    gld_lds16(Kg1 + koff, &Ks[buf][(tid+256)*8]); \
    gld_lds16(Vg0 + voff, &Vs[buf][tid*8]); \
    gld_lds16(Vg1 + voff, &Vs[buf][(tid+256)*8]); }

  ATTN_STAGE(0, 0);

  short8 qa[2][2];
  {
    const unsigned short* qp0 = Qb + (size_t)(qb*128 + w*32 + l15)*ED + h*HD + l4*8;
    qa[0][0] = *(const short8*)qp0;
    qa[0][1] = *(const short8*)(qp0 + 32);
    const unsigned short* qp1 = qp0 + (size_t)16*ED;
    qa[1][0] = *(const short8*)qp1;
    qa[1][1] = *(const short8*)(qp1 + 32);
  }

  unsigned* Pw = &Psu[w][0];
  f32x4 o_acc[2][4] = {};
  float l_acc[2][4] = {{0.f,0.f,0.f,0.f},{0.f,0.f,0.f,0.f}};
  __syncthreads();

  for(int kb=0; kb<SEQ/64; kb++){
    const int cur = kb & 1;
    if (kb+1 < SEQ/64) ATTN_STAGE(cur^1, kb+1);

    __builtin_amdgcn_s_setprio(1);
    f32x4 s_acc[2][4] = {};
#pragma unroll
    for(int n=0;n<4;n++){
      int key = n*16 + l15;
#pragma unroll
      for(int ks=0;ks<2;ks++){
        short8 kf = *(const short8*)&Ks[cur][key*64 + (((ks*4+l4) ^ (key&7))*8)];
        s_acc[0][n] = __builtin_amdgcn_mfma_f32_16x16x32_bf16(qa[0][ks], kf, s_acc[0][n], 0,0,0);
        s_acc[1][n] = __builtin_amdgcn_mfma_f32_16x16x32_bf16(qa[1][ks], kf, s_acc[1][n], 0,0,0);
      }
    }
    __builtin_amdgcn_s_setprio(0);

#pragma unroll
    for(int mt=0;mt<2;mt++){
#pragma unroll
      for(int r=0;r<4;r++){
        float p0 = fexp2(s_acc[mt][0][r]), p1 = fexp2(s_acc[mt][1][r]);
        float p2 = fexp2(s_acc[mt][2][r]), p3 = fexp2(s_acc[mt][3][r]);
        l_acc[mt][r] += (p0+p1)+(p2+p3);
        unsigned u01, u23;
        asm("v_cvt_pk_bf16_f32 %0, %1, %2" : "=v"(u01) : "v"(p0), "v"(p1));
        asm("v_cvt_pk_bf16_f32 %0, %1, %2" : "=v"(u23) : "v"(p2), "v"(p3));
        const int q32 = mt*16 + l4*4 + r;
        Pw[q32*32 + (((l15>>2)     ^ (q32&7))<<2) + (l15&3)] = u01;
        Pw[q32*32 + (((4+(l15>>2)) ^ (q32&7))<<2) + (l15&3)] = u23;
      }
    }
    asm volatile("s_waitcnt lgkmcnt(0)" ::: "memory");

    __builtin_amdgcn_s_setprio(1);
#pragma unroll
    for(int ks=0;ks<2;ks++){
      short8 pa0 = *(const short8*)&Pw[(l15   )*32 + (((ks*4+l4) ^ (l15&7))<<2)];
      short8 pa1 = *(const short8*)&Pw[(16+l15)*32 + (((ks*4+l4) ^ (l15&7))<<2)];
#pragma unroll
      for(int n=0;n<4;n++){
        int d = n*16 + l15;
        short8 vf = *(const short8*)&Vs[cur][d*64 + (((ks*4+l4) ^ (d&7))*8)];
        o_acc[0][n] = __builtin_amdgcn_mfma_f32_16x16x32_bf16(pa0, vf, o_acc[0][n], 0,0,0);
        o_acc[1][n] = __builtin_amdgcn_mfma_f32_16x16x32_bf16(pa1, vf, o_acc[1][n], 0,0,0);
      }
    }
    __builtin_amdgcn_s_setprio(0);
    __syncthreads();
  }
#undef ATTN_STAGE

#pragma unroll
  for(int mt=0;mt<2;mt++)
#pragma unroll
    for(int r=0;r<4;r++){
      float t = l_acc[mt][r];
      t += __shfl_xor(t,1); t += __shfl_xor(t,2); t += __shfl_xor(t,4); t += __shfl_xor(t,8);
      l_acc[mt][r] = 1.0f / t;
    }
#pragma unroll
  for(int mt=0;mt<2;mt++)
#pragma unroll
    for(int n=0;n<4;n++){
      const int col = h*HD + n*16 + l15;
#pragma unroll
      for(int r=0;r<4;r++){
        const int srow = qb*128 + w*32 + mt*16 + l4*4 + r;
        Ob[(size_t)srow*ED + col] = f2bf(o_acc[mt][n][r] * l_acc[mt][r]);
      }
    }
}

extern "C" void kernel_launch(void* const* d_in, const int* in_sizes, int n_in,
                              void* d_out, int out_size, void* d_ws, size_t ws_size,
                              hipStream_t stream) {
  const float* Xq    = (const float*)d_in[0];
  const float* Xkv   = (const float*)d_in[1];
  const float* cos_q = (const float*)d_in[2];
  const float* sin_q = (const float*)d_in[3];
  const float* cos_k = (const float*)d_in[4];
  const float* sin_k = (const float*)d_in[5];
  const float* wq = (const float*)d_in[7];
  const float* wk = (const float*)d_in[8];
  const float* wv = (const float*)d_in[9];
  const float* wo = (const float*)d_in[10];
  float* out = (float*)d_out;

  char* ws = (char*)d_ws;
  const size_t MB = 1u<<20;
  unsigned short* Xb   = (unsigned short*)(ws + 0*MB);
  unsigned short* KVb  = (unsigned short*)(ws + 8*MB);
  unsigned short* Wqb  = (unsigned short*)(ws + 16*MB);
  unsigned short* WKVb = (unsigned short*)(ws + 24*MB);
  unsigned short* Wob  = (unsigned short*)(ws + 28*MB);
  unsigned short* Qb   = (unsigned short*)(ws + 36*MB);
  unsigned short* Kb   = (unsigned short*)(ws + 44*MB);
  unsigned short* Vtb  = (unsigned short*)(ws + 46*MB);
  unsigned short* Obf  = (unsigned short*)(ws + 48*MB);

  cvt_all<<<9216,256,0,stream>>>(Xq, Xkv, wq, wk, wv, wo, Xb, KVb, Wqb, WKVb, Wob);

  gemm_proj<<<768,256,0,stream>>>(Xb, Wqb, KVb, WKVb, Qb, Kb, Vtb);

  rope_all<<<2560,256,0,stream>>>(Qb, Kb, cos_q, sin_q, cos_k, sin_k);

  attn_k<<<dim3(SEQ/128, NHEADS),256,0,stream>>>(Qb, Kb, Vtb, Obf);

  gemm_out_k<<<512,256,0,stream>>>(Obf, Wob, out);
}